// Round 3
// baseline (414.293 us; speedup 1.0000x reference)
//
#include <hip/hip_runtime.h>
#include <hip/hip_bf16.h>

// ArcFace fused: cos = emb @ (w/||w||), margin on target label, softmax over batch axis.
// N=512, D=512, C=100000, S=1.
// Pipeline (all streaming / BW-bound except main):
//   label_scan : tgt one-hot -> labels[512]
//   norm_part  : w f32 -> partial column norms (4 k-chunks)
//   norm_reduce: partials -> rnorm[c] = rsqrt(sum)
//   wt_kernel  : w * rnorm -> bf16, TRANSPOSED w_bfT[c][k] (LDS tile transpose)
//   prep_afrag : emb f32 -> bf16 A-fragments (512 KB, L2-resident)
//   arcface_main: zero-LDS K-loop; A and B fragments are single dwordx4 loads;
//                 margin via label compare; in-block column softmax.

static constexpr int DIM    = 512;     // D (= K of the GEMM)
static constexpr int NROWS  = 512;     // N (batch; = M of the GEMM)
static constexpr int NCLS   = 100000;  // C
static constexpr int BC     = 64;      // columns per block
static constexpr int BK     = 32;      // K per step (one MFMA K)
static constexpr int NSTEP  = DIM / BK;        // 16
static constexpr int MT     = NROWS / 16;      // 32 M-tiles
static constexpr int NBLK   = (NCLS + BC - 1) / BC;  // 1563
static constexpr int CPAD   = 100352;  // padded C for partials (98*1024)
static constexpr int CROWS  = NBLK * BC;       // 100032 padded rows of w_bfT

static constexpr float COS_M = 0.87758256189037271611f;  // cos(0.5)
static constexpr float SIN_M = 0.47942553860420300027f;  // sin(0.5)
static constexpr float SCALE = 64.0f;

typedef __attribute__((ext_vector_type(8))) short bf16x8;
typedef __attribute__((ext_vector_type(4))) float f32x4;

// ws layout (bytes)
static constexpr size_t WS_LABELS = 0;          // 512 * 4
static constexpr size_t WS_AFRAG  = 4096;       // 512 KB
static constexpr size_t WS_NPART  = 1u << 20;   // 4 * CPAD * 4 = 1.6 MB
static constexpr size_t WS_RNORM  = 4u << 20;   // CPAD * 4
static constexpr size_t WS_WBFT   = 8u << 20;   // CROWS * 512 * 2 = 102.4 MB
static constexpr size_t WS_NEED   = WS_WBFT + (size_t)CROWS * DIM * 2;
static constexpr size_t WS_NEED_FB = WS_AFRAG + 512 * 1024;

__device__ __forceinline__ unsigned short f2bf(float f) {
  union { float f; unsigned u; } v; v.f = f;
  unsigned u = v.u;
  return (unsigned short)((u + 0x7FFFu + ((u >> 16) & 1u)) >> 16);
}

// ---------------------------------------------------------------------------
// tgt [512][100000] one-hot -> labels[512]
// ---------------------------------------------------------------------------
__global__ __launch_bounds__(1024)
void label_scan(const float* __restrict__ tgt, int* __restrict__ labels) {
  const int row = blockIdx.x;
  const float4* rp = reinterpret_cast<const float4*>(tgt + (size_t)row * NCLS);
  int found = -1;
  for (int c4 = threadIdx.x; c4 < NCLS / 4; c4 += 1024) {
    const float4 v = rp[c4];
    if (v.x > 0.5f) found = c4 * 4 + 0;
    if (v.y > 0.5f) found = c4 * 4 + 1;
    if (v.z > 0.5f) found = c4 * 4 + 2;
    if (v.w > 0.5f) found = c4 * 4 + 3;
  }
  if (found >= 0) labels[row] = found;
}

// ---------------------------------------------------------------------------
// Partial column norms. grid (98, 4), 256 threads; thread owns 4 cols (float4).
// ---------------------------------------------------------------------------
__global__ __launch_bounds__(256)
void norm_part(const float* __restrict__ w, float* __restrict__ part) {
  const int c4 = blockIdx.x * 256 + threadIdx.x;   // float4 index
  const int cb = c4 * 4;
  const int kc = blockIdx.y;
  float4 s = {0.f, 0.f, 0.f, 0.f};
  if (cb + 3 < NCLS) {
    const float4* w4 = reinterpret_cast<const float4*>(w);
    for (int k = kc * 128; k < kc * 128 + 128; ++k) {
      const float4 v = w4[(size_t)k * (NCLS / 4) + c4];
      s.x += v.x * v.x; s.y += v.y * v.y; s.z += v.z * v.z; s.w += v.w * v.w;
    }
  } else {
    for (int k = kc * 128; k < kc * 128 + 128; ++k) {
      const size_t rb = (size_t)k * NCLS;
      if (cb + 0 < NCLS) s.x += w[rb + cb + 0] * w[rb + cb + 0];
      if (cb + 1 < NCLS) s.y += w[rb + cb + 1] * w[rb + cb + 1];
      if (cb + 2 < NCLS) s.z += w[rb + cb + 2] * w[rb + cb + 2];
      if (cb + 3 < NCLS) s.w += w[rb + cb + 3] * w[rb + cb + 3];
    }
  }
  *reinterpret_cast<float4*>(&part[(size_t)kc * CPAD + cb]) = s;
}

__global__ __launch_bounds__(256)
void norm_reduce(const float* __restrict__ part, float* __restrict__ rnorm) {
  const int c4 = blockIdx.x * 256 + threadIdx.x;
  const float4* p4 = reinterpret_cast<const float4*>(part);
  float4 s = {0.f, 0.f, 0.f, 0.f};
#pragma unroll
  for (int kc = 0; kc < 4; ++kc) {
    const float4 v = p4[(size_t)kc * (CPAD / 4) + c4];
    s.x += v.x; s.y += v.y; s.z += v.z; s.w += v.w;
  }
  float4 r;
  r.x = rsqrtf(fmaxf(s.x, 1e-20f));
  r.y = rsqrtf(fmaxf(s.y, 1e-20f));
  r.z = rsqrtf(fmaxf(s.z, 1e-20f));
  r.w = rsqrtf(fmaxf(s.w, 1e-20f));
  *reinterpret_cast<float4*>(&rnorm[c4 * 4]) = r;
}

// ---------------------------------------------------------------------------
// w [k][c] f32 -> w_bfT [c][k] bf16, normalized. Tile 64k x 64c via LDS.
// grid (1563 c-tiles, 8 k-tiles), 256 threads.
// ---------------------------------------------------------------------------
__global__ __launch_bounds__(256)
void wt_kernel(const float* __restrict__ w, const float* __restrict__ rnorm,
               unsigned short* __restrict__ wbft) {
  __shared__ unsigned short T[64][66];   // pad 66: write banks (33c+k/2)%32 -> 2-way max
  const int tid = threadIdx.x;
  const int c0 = blockIdx.x * 64;
  const int k0 = blockIdx.y * 64;

  const int cc = tid & 63;
  const bool cok = (c0 + cc) < NCLS;
  const float rn = cok ? rnorm[c0 + cc] : 0.f;

#pragma unroll
  for (int pass = 0; pass < 16; ++pass) {
    const int kk = (tid >> 6) + pass * 4;
    const float v = cok ? w[(size_t)(k0 + kk) * NCLS + c0 + cc] * rn : 0.f;
    T[cc][kk] = f2bf(v);
  }
  __syncthreads();

  // write: thread -> (c = tid>>2, 16-k chunk q = tid&3); 32B per thread
  const int c = tid >> 2;
  const int q = tid & 3;
  uint4 lo, hi;
  const unsigned* src = reinterpret_cast<const unsigned*>(&T[c][q * 16]);
  lo.x = src[0]; lo.y = src[1]; lo.z = src[2]; lo.w = src[3];
  hi.x = src[4]; hi.y = src[5]; hi.z = src[6]; hi.w = src[7];
  unsigned short* dst = wbft + (size_t)(c0 + c) * DIM + k0 + q * 16;
  *reinterpret_cast<uint4*>(dst)     = lo;
  *reinterpret_cast<uint4*>(dst + 8) = hi;
}

// ---------------------------------------------------------------------------
// emb [512][512] f32 -> bf16 A-fragments
// ---------------------------------------------------------------------------
__global__ void prep_afrag(const float* __restrict__ emb,
                           unsigned short* __restrict__ afrag) {
  const int idx = blockIdx.x * blockDim.x + threadIdx.x;  // 0..32767
  const int l  = idx & 63;
  const int mt = (idx >> 6) & 31;
  const int ks = idx >> 11;
  const int row = mt * 16 + (l & 15);
  const int k0  = ks * 32 + (l >> 4) * 8;

  unsigned short t[8];
#pragma unroll
  for (int j = 0; j < 8; ++j) t[j] = f2bf(emb[row * DIM + k0 + j]);

  uint4 v;
  v.x = (unsigned)t[0] | ((unsigned)t[1] << 16);
  v.y = (unsigned)t[2] | ((unsigned)t[3] << 16);
  v.z = (unsigned)t[4] | ((unsigned)t[5] << 16);
  v.w = (unsigned)t[6] | ((unsigned)t[7] << 16);
  *reinterpret_cast<uint4*>(&afrag[(size_t)idx * 8]) = v;
}

// ---------------------------------------------------------------------------
// Main fused kernel (fast path). 512 threads = 8 waves.
// Wave wv: rows [wv*64, wv*64+64) x 64 block cols. Zero LDS in K-loop.
// ---------------------------------------------------------------------------
__global__ __launch_bounds__(512)
void arcface_main(const unsigned short* __restrict__ wbft,
                  const int* __restrict__ labels,
                  const unsigned short* __restrict__ afrag,
                  float* __restrict__ out) {
  __shared__ float red[8][BC];
  __shared__ float colv[BC];

  const int tid = threadIdx.x;
  const int wv  = tid >> 6;
  const int l   = tid & 63;
  const int lh  = l >> 4;
  const int ll  = l & 15;
  const int c0  = blockIdx.x * BC;

  int cj[4];
  const unsigned short* pB[4];
#pragma unroll
  for (int j = 0; j < 4; ++j) {
    cj[j] = c0 + j * 16 + ll;
    pB[j] = wbft + (size_t)cj[j] * DIM + lh * 8;   // padded rows: always in-bounds
  }
  const unsigned short* pA[4];
#pragma unroll
  for (int i = 0; i < 4; ++i)
    pA[i] = afrag + ((size_t)(wv * 4 + i) * 64 + l) * 8;

  f32x4 acc[4][4] = {};

#pragma unroll 4
  for (int ks = 0; ks < NSTEP; ++ks) {
    bf16x8 a[4], b[4];
#pragma unroll
    for (int j = 0; j < 4; ++j)
      b[j] = *reinterpret_cast<const bf16x8*>(pB[j] + ks * BK);
#pragma unroll
    for (int i = 0; i < 4; ++i)
      a[i] = *reinterpret_cast<const bf16x8*>(pA[i] + (size_t)ks * MT * 64 * 8);
#pragma unroll
    for (int i = 0; i < 4; ++i)
#pragma unroll
      for (int j = 0; j < 4; ++j)
        acc[i][j] = __builtin_amdgcn_mfma_f32_16x16x32_bf16(a[i], b[j], acc[i][j], 0, 0, 0);
  }

  // labels for my 16 rows
  int lab[4][4];
#pragma unroll
  for (int i = 0; i < 4; ++i)
#pragma unroll
    for (int q = 0; q < 4; ++q)
      lab[i][q] = labels[wv * 64 + i * 16 + lh * 4 + q];

  // logits: clip -> margin at target -> *64; track per-column max
  float mx[4];
#pragma unroll
  for (int j = 0; j < 4; ++j) mx[j] = -3.4e38f;
#pragma unroll
  for (int j = 0; j < 4; ++j) {
#pragma unroll
    for (int i = 0; i < 4; ++i) {
#pragma unroll
      for (int q = 0; q < 4; ++q) {
        float cosv = acc[i][j][q];
        cosv = fminf(fmaxf(cosv, -1.f), 1.f);
        float lg;
        if (lab[i][q] == cj[j]) {
          const float s = sqrtf(fmaxf(1.f - cosv * cosv, 0.f));
          lg = cosv * COS_M - s * SIN_M;
        } else {
          lg = cosv;
        }
        lg *= SCALE;
        acc[i][j][q] = lg;
        mx[j] = fmaxf(mx[j], lg);
      }
    }
  }

  // softmax over the 512 rows of each column
#pragma unroll
  for (int j = 0; j < 4; ++j) {
    mx[j] = fmaxf(mx[j], __shfl_xor(mx[j], 16, 64));
    mx[j] = fmaxf(mx[j], __shfl_xor(mx[j], 32, 64));
  }
  if (l < 16) {
#pragma unroll
    for (int j = 0; j < 4; ++j) red[wv][j * 16 + l] = mx[j];
  }
  __syncthreads();
  if (tid < BC) {
    float m = red[0][tid];
#pragma unroll
    for (int v2 = 1; v2 < 8; ++v2) m = fmaxf(m, red[v2][tid]);
    colv[tid] = m;
  }
  __syncthreads();
  float cmax[4];
#pragma unroll
  for (int j = 0; j < 4; ++j) cmax[j] = colv[j * 16 + ll];

  float sme[4] = {0.f, 0.f, 0.f, 0.f};
#pragma unroll
  for (int j = 0; j < 4; ++j)
#pragma unroll
    for (int i = 0; i < 4; ++i)
#pragma unroll
      for (int q = 0; q < 4; ++q) {
        const float e = __expf(acc[i][j][q] - cmax[j]);
        acc[i][j][q] = e;
        sme[j] += e;
      }
#pragma unroll
  for (int j = 0; j < 4; ++j) {
    sme[j] += __shfl_xor(sme[j], 16, 64);
    sme[j] += __shfl_xor(sme[j], 32, 64);
  }
  __syncthreads();
  if (l < 16) {
#pragma unroll
    for (int j = 0; j < 4; ++j) red[wv][j * 16 + l] = sme[j];
  }
  __syncthreads();
  if (tid < BC) {
    float s = 0.f;
#pragma unroll
    for (int v2 = 0; v2 < 8; ++v2) s += red[v2][tid];
    colv[tid] = s;
  }
  __syncthreads();

  float rs[4];
#pragma unroll
  for (int j = 0; j < 4; ++j) rs[j] = 1.0f / colv[j * 16 + ll];

#pragma unroll
  for (int j = 0; j < 4; ++j) {
    if (cj[j] >= NCLS) continue;
#pragma unroll
    for (int i = 0; i < 4; ++i) {
#pragma unroll
      for (int q = 0; q < 4; ++q) {
        const int row = wv * 64 + i * 16 + lh * 4 + q;
        out[(size_t)row * NCLS + cj[j]] = acc[i][j][q] * rs[j];
      }
    }
  }
}

// ---------------------------------------------------------------------------
// Fallback main kernel (round-2 path): B from global f32, norms in-kernel.
// Used only if ws_size < WS_NEED.
// ---------------------------------------------------------------------------
__global__ __launch_bounds__(512)
void arcface_main_fb(const float* __restrict__ w,
                     const int* __restrict__ labels,
                     const unsigned short* __restrict__ afrag,
                     float* __restrict__ out) {
  __shared__ float red[8][BC];
  __shared__ float colv[BC];

  const int tid = threadIdx.x;
  const int wv  = tid >> 6;
  const int l   = tid & 63;
  const int lh  = l >> 4;
  const int ll  = l & 15;
  const int c0  = blockIdx.x * BC;

  int cj[4]; size_t ccol[4];
#pragma unroll
  for (int j = 0; j < 4; ++j) {
    cj[j] = c0 + j * 16 + ll;
    ccol[j] = (size_t)(cj[j] < NCLS ? cj[j] : NCLS - 1);
  }

  f32x4 acc[4][4] = {};
  float nrm[4] = {0.f, 0.f, 0.f, 0.f};

  for (int ks = 0; ks < NSTEP; ++ks) {
    float bx[4][8];
    const size_t rowbase = (size_t)(ks * BK + lh * 8) * NCLS;
#pragma unroll
    for (int j = 0; j < 4; ++j) {
      const float* p = w + rowbase + ccol[j];
#pragma unroll
      for (int e = 0; e < 8; ++e) bx[j][e] = p[(size_t)e * NCLS];
    }
    bf16x8 a[4];
#pragma unroll
    for (int i = 0; i < 4; ++i)
      a[i] = *reinterpret_cast<const bf16x8*>(
          &afrag[((size_t)(ks * MT + wv * 4 + i) * 64 + l) * 8]);
    bf16x8 b[4];
#pragma unroll
    for (int j = 0; j < 4; ++j) {
#pragma unroll
      for (int e = 0; e < 8; ++e) nrm[j] += bx[j][e] * bx[j][e];
#pragma unroll
      for (int e = 0; e < 8; ++e) b[j][e] = (short)f2bf(bx[j][e]);
    }
#pragma unroll
    for (int i = 0; i < 4; ++i)
#pragma unroll
      for (int j = 0; j < 4; ++j)
        acc[i][j] = __builtin_amdgcn_mfma_f32_16x16x32_bf16(a[i], b[j], acc[i][j], 0, 0, 0);
  }

  float rn[4];
#pragma unroll
  for (int j = 0; j < 4; ++j) {
    nrm[j] += __shfl_xor(nrm[j], 16, 64);
    nrm[j] += __shfl_xor(nrm[j], 32, 64);
    rn[j] = rsqrtf(fmaxf(nrm[j], 1e-20f));
  }

  int lab[4][4];
#pragma unroll
  for (int i = 0; i < 4; ++i)
#pragma unroll
    for (int q = 0; q < 4; ++q)
      lab[i][q] = labels[wv * 64 + i * 16 + lh * 4 + q];

  float mx[4];
#pragma unroll
  for (int j = 0; j < 4; ++j) mx[j] = -3.4e38f;
#pragma unroll
  for (int j = 0; j < 4; ++j) {
#pragma unroll
    for (int i = 0; i < 4; ++i) {
#pragma unroll
      for (int q = 0; q < 4; ++q) {
        float cosv = acc[i][j][q] * rn[j];
        cosv = fminf(fmaxf(cosv, -1.f), 1.f);
        float lg;
        if (lab[i][q] == cj[j]) {
          const float s = sqrtf(fmaxf(1.f - cosv * cosv, 0.f));
          lg = cosv * COS_M - s * SIN_M;
        } else {
          lg = cosv;
        }
        lg *= SCALE;
        acc[i][j][q] = lg;
        mx[j] = fmaxf(mx[j], lg);
      }
    }
  }

#pragma unroll
  for (int j = 0; j < 4; ++j) {
    mx[j] = fmaxf(mx[j], __shfl_xor(mx[j], 16, 64));
    mx[j] = fmaxf(mx[j], __shfl_xor(mx[j], 32, 64));
  }
  if (l < 16) {
#pragma unroll
    for (int j = 0; j < 4; ++j) red[wv][j * 16 + l] = mx[j];
  }
  __syncthreads();
  if (tid < BC) {
    float m = red[0][tid];
#pragma unroll
    for (int v2 = 1; v2 < 8; ++v2) m = fmaxf(m, red[v2][tid]);
    colv[tid] = m;
  }
  __syncthreads();
  float cmax[4];
#pragma unroll
  for (int j = 0; j < 4; ++j) cmax[j] = colv[j * 16 + ll];

  float sme[4] = {0.f, 0.f, 0.f, 0.f};
#pragma unroll
  for (int j = 0; j < 4; ++j)
#pragma unroll
    for (int i = 0; i < 4; ++i)
#pragma unroll
      for (int q = 0; q < 4; ++q) {
        const float e = __expf(acc[i][j][q] - cmax[j]);
        acc[i][j][q] = e;
        sme[j] += e;
      }
#pragma unroll
  for (int j = 0; j < 4; ++j) {
    sme[j] += __shfl_xor(sme[j], 16, 64);
    sme[j] += __shfl_xor(sme[j], 32, 64);
  }
  __syncthreads();
  if (l < 16) {
#pragma unroll
    for (int j = 0; j < 4; ++j) red[wv][j * 16 + l] = sme[j];
  }
  __syncthreads();
  if (tid < BC) {
    float s = 0.f;
#pragma unroll
    for (int v2 = 0; v2 < 8; ++v2) s += red[v2][tid];
    colv[tid] = s;
  }
  __syncthreads();

  float rs[4];
#pragma unroll
  for (int j = 0; j < 4; ++j) rs[j] = 1.0f / colv[j * 16 + ll];

#pragma unroll
  for (int j = 0; j < 4; ++j) {
    if (cj[j] >= NCLS) continue;
#pragma unroll
    for (int i = 0; i < 4; ++i) {
#pragma unroll
      for (int q = 0; q < 4; ++q) {
        const int row = wv * 64 + i * 16 + lh * 4 + q;
        out[(size_t)row * NCLS + cj[j]] = acc[i][j][q] * rs[j];
      }
    }
  }
}

extern "C" void kernel_launch(void* const* d_in, const int* in_sizes, int n_in,
                              void* d_out, int out_size, void* d_ws, size_t ws_size,
                              hipStream_t stream) {
  const float* emb = (const float*)d_in[0];   // [512][512]
  const float* w   = (const float*)d_in[1];   // [512][100000]
  const float* tgt = (const float*)d_in[2];   // [512][100000]
  float* out = (float*)d_out;                 // [512][100000]

  char* ws = (char*)d_ws;
  int* labels = (int*)(ws + WS_LABELS);
  unsigned short* afrag = (unsigned short*)(ws + WS_AFRAG);

  label_scan<<<NROWS, 1024, 0, stream>>>(tgt, labels);
  prep_afrag<<<64, 512, 0, stream>>>(emb, afrag);

  if (ws_size >= WS_NEED) {
    float* part  = (float*)(ws + WS_NPART);
    float* rnorm = (float*)(ws + WS_RNORM);
    unsigned short* wbft = (unsigned short*)(ws + WS_WBFT);

    norm_part<<<dim3(CPAD / 1024, 4), 256, 0, stream>>>(w, part);
    norm_reduce<<<CPAD / 1024, 256, 0, stream>>>(part, rnorm);
    wt_kernel<<<dim3(NBLK, DIM / 64), 256, 0, stream>>>(w, rnorm, wbft);
    arcface_main<<<NBLK, 512, 0, stream>>>(wbft, labels, afrag, out);
  } else {
    arcface_main_fb<<<NBLK, 512, 0, stream>>>(w, labels, afrag, out);
  }
}

// Round 4
// 292.559 us; speedup vs baseline: 1.4161x; 1.4161x over previous
//
#include <hip/hip_runtime.h>
#include <hip/hip_bf16.h>

// ArcFace fused: cos = emb @ (w/||w||), margin at target label, softmax over batch axis.
// N=512, D=512, C=100000, S=1.
//   label_scan   : tgt one-hot -> labels[512] (streaming, BW-bound)
//   prep_afrag   : emb f32 -> bf16 A-fragments (512 KB, L2-resident)
//   arcface_fused: ONE pass over w f32. Per block (64 cols x 512 rows), per K-step:
//                  [prefetch next f32 tile to regs] stage f32->LDS (+norm FMA) ->
//                  in-LDS transpose to bf16 fragment layout -> ds_read_b128 + MFMA.
//                  Norm finish + margin + in-block column softmax in epilogue.

static constexpr int DIM    = 512;
static constexpr int NROWS  = 512;
static constexpr int NCLS   = 100000;
static constexpr int BC     = 64;              // columns per block
static constexpr int BK     = 32;              // K per step
static constexpr int NSTEP  = DIM / BK;        // 16
static constexpr int MT     = NROWS / 16;      // 32
static constexpr int NBLK   = (NCLS + BC - 1) / BC;  // 1563

static constexpr float COS_M = 0.87758256189037271611f;  // cos(0.5)
static constexpr float SIN_M = 0.47942553860420300027f;  // sin(0.5)
static constexpr float SCALE = 64.0f;

typedef __attribute__((ext_vector_type(8))) short bf16x8;
typedef __attribute__((ext_vector_type(4))) float f32x4;

__device__ __forceinline__ unsigned short f2bf(float f) {
  union { float f; unsigned u; } v; v.f = f;
  unsigned u = v.u;
  return (unsigned short)((u + 0x7FFFu + ((u >> 16) & 1u)) >> 16);
}

// ---------------------------------------------------------------------------
// tgt [512][100000] one-hot -> labels[512]. grid (512 rows, 4 chunks).
// ---------------------------------------------------------------------------
__global__ __launch_bounds__(1024)
void label_scan(const float* __restrict__ tgt, int* __restrict__ labels) {
  const int row = blockIdx.x;
  const int nq = NCLS / 4;                       // 25000 float4s
  const int q0 = blockIdx.y * (nq / 4);          // 4 chunks of 6250
  const int q1 = (blockIdx.y == 3) ? nq : q0 + (nq / 4);
  const float4* rp = reinterpret_cast<const float4*>(tgt + (size_t)row * NCLS);
  int found = -1;
  for (int c4 = q0 + threadIdx.x; c4 < q1; c4 += 1024) {
    const float4 v = rp[c4];
    if (v.x > 0.5f) found = c4 * 4 + 0;
    if (v.y > 0.5f) found = c4 * 4 + 1;
    if (v.z > 0.5f) found = c4 * 4 + 2;
    if (v.w > 0.5f) found = c4 * 4 + 3;
  }
  if (found >= 0) labels[row] = found;           // exactly one writer per row
}

// ---------------------------------------------------------------------------
// emb [512][512] f32 -> bf16 A-fragments:
// afrag[((ks*MT+mt)*64 + lane)*8 + j] = bf16(emb[mt*16 + (lane&15)][ks*32 + (lane>>4)*8 + j])
// ---------------------------------------------------------------------------
__global__ void prep_afrag(const float* __restrict__ emb,
                           unsigned short* __restrict__ afrag) {
  const int idx = blockIdx.x * blockDim.x + threadIdx.x;  // 0..32767
  const int l  = idx & 63;
  const int mt = (idx >> 6) & 31;
  const int ks = idx >> 11;
  const int row = mt * 16 + (l & 15);
  const int k0  = ks * 32 + (l >> 4) * 8;

  unsigned short t[8];
#pragma unroll
  for (int j = 0; j < 8; ++j) t[j] = f2bf(emb[row * DIM + k0 + j]);

  uint4 v;
  v.x = (unsigned)t[0] | ((unsigned)t[1] << 16);
  v.y = (unsigned)t[2] | ((unsigned)t[3] << 16);
  v.z = (unsigned)t[4] | ((unsigned)t[5] << 16);
  v.w = (unsigned)t[6] | ((unsigned)t[7] << 16);
  *reinterpret_cast<uint4*>(&afrag[(size_t)idx * 8]) = v;
}

// ---------------------------------------------------------------------------
// guarded float4 load of w[k][cg..cg+3]
// ---------------------------------------------------------------------------
__device__ __forceinline__ float4 ldw(const float* __restrict__ w, int k, int cg) {
  if (cg + 3 < NCLS)
    return *reinterpret_cast<const float4*>(w + (size_t)k * NCLS + cg);
  float4 r = {0.f, 0.f, 0.f, 0.f};
  const size_t rb = (size_t)k * NCLS;
  if (cg + 0 < NCLS) r.x = w[rb + cg + 0];
  if (cg + 1 < NCLS) r.y = w[rb + cg + 1];
  if (cg + 2 < NCLS) r.z = w[rb + cg + 2];
  if (cg + 3 < NCLS) r.w = w[rb + cg + 3];
  return r;
}

// ---------------------------------------------------------------------------
// Main fused kernel. 512 threads = 8 waves. Wave wv owns rows [wv*64, wv*64+64).
// ---------------------------------------------------------------------------
__global__ __launch_bounds__(512)
void arcface_fused(const float* __restrict__ w,
                   const int* __restrict__ labels,
                   const unsigned short* __restrict__ afrag,
                   float* __restrict__ out) {
  __shared__ float S1[BK][68];                    // staged f32 tile (pad 68)
  __shared__ alignas(16) unsigned short S2[256][8]; // bf16 fragments [lh*64+c][e]
  __shared__ float red[8][BC];
  __shared__ float colv[BC];
  __shared__ float rnS[BC];

  const int tid = threadIdx.x;
  const int wv  = tid >> 6;
  const int l   = tid & 63;
  const int lh  = l >> 4;
  const int ll  = l & 15;
  const int c0  = blockIdx.x * BC;

  // staging role: thread stages k-row sk, cols scg..scg+3
  const int sk  = tid >> 4;        // 0..31
  const int sc4 = tid & 15;
  const int scg = c0 + sc4 * 4;

  int cj[4];
#pragma unroll
  for (int j = 0; j < 4; ++j) cj[j] = c0 + j * 16 + ll;

  const unsigned short* pA[4];
#pragma unroll
  for (int i = 0; i < 4; ++i)
    pA[i] = afrag + ((size_t)(wv * 4 + i) * 64 + l) * 8;

  f32x4 acc[4][4] = {};
  float4 nrm4 = {0.f, 0.f, 0.f, 0.f};

  // prologue: load step-0 tile into regs
  float4 v = ldw(w, sk, scg);

  for (int ks = 0; ks < NSTEP; ++ks) {
    // prefetch next step's tile (in flight across this whole step)
    float4 vn = {0.f, 0.f, 0.f, 0.f};
    if (ks + 1 < NSTEP) vn = ldw(w, (ks + 1) * BK + sk, scg);

    // A fragments for this step (L2-resident; issue early, consumed in phase 3)
    bf16x8 a[4];
#pragma unroll
    for (int i = 0; i < 4; ++i)
      a[i] = *reinterpret_cast<const bf16x8*>(pA[i] + (size_t)ks * MT * 64 * 8);

    __syncthreads();   // B1: S1 readers (prev transpose) and S2 readers (prev MFMA) done

    // phase 1: norms + stage f32 tile
    nrm4.x += v.x * v.x; nrm4.y += v.y * v.y;
    nrm4.z += v.z * v.z; nrm4.w += v.w * v.w;
    *reinterpret_cast<float4*>(&S1[sk][sc4 * 4]) = v;

    __syncthreads();   // B2

    // phase 2: transpose 32x64 f32 -> bf16 fragment layout (first 4 waves)
    if (tid < 256) {
      const int tc = tid & 63;    // column
      const int tl = tid >> 6;    // k-half group 0..3
      float x[8];
#pragma unroll
      for (int e = 0; e < 8; ++e) x[e] = S1[tl * 8 + e][tc];
      uint4 pk;
      pk.x = (unsigned)f2bf(x[0]) | ((unsigned)f2bf(x[1]) << 16);
      pk.y = (unsigned)f2bf(x[2]) | ((unsigned)f2bf(x[3]) << 16);
      pk.z = (unsigned)f2bf(x[4]) | ((unsigned)f2bf(x[5]) << 16);
      pk.w = (unsigned)f2bf(x[6]) | ((unsigned)f2bf(x[7]) << 16);
      *reinterpret_cast<uint4*>(&S2[tl * 64 + tc][0]) = pk;
    }

    __syncthreads();   // B3

    // phase 3: B fragments from LDS (one ds_read_b128 each) + MFMA
    bf16x8 b[4];
#pragma unroll
    for (int j = 0; j < 4; ++j)
      b[j] = *reinterpret_cast<const bf16x8*>(&S2[lh * 64 + j * 16 + ll][0]);
#pragma unroll
    for (int i = 0; i < 4; ++i)
#pragma unroll
      for (int j = 0; j < 4; ++j)
        acc[i][j] = __builtin_amdgcn_mfma_f32_16x16x32_bf16(a[i], b[j], acc[i][j], 0, 0, 0);

    v = vn;
  }

  // ---- finish column norms: reuse S1 for partials
  __syncthreads();
  *reinterpret_cast<float4*>(&S1[sk][sc4 * 4]) = nrm4;
  __syncthreads();
  if (tid < BC) {
    float s = 0.f;
#pragma unroll
    for (int k = 0; k < BK; ++k) s += S1[k][tid];
    rnS[tid] = rsqrtf(fmaxf(s, 1e-20f));
  }
  __syncthreads();
  float rn[4];
#pragma unroll
  for (int j = 0; j < 4; ++j) rn[j] = rnS[j * 16 + ll];

  // ---- labels for my 16 rows (L2-hot)
  int lab[4][4];
#pragma unroll
  for (int i = 0; i < 4; ++i)
#pragma unroll
    for (int q = 0; q < 4; ++q)
      lab[i][q] = labels[wv * 64 + i * 16 + lh * 4 + q];

  // ---- logits: cos*rn -> clip -> margin at target -> *64; track col max
  float mx[4];
#pragma unroll
  for (int j = 0; j < 4; ++j) mx[j] = -3.4e38f;
#pragma unroll
  for (int j = 0; j < 4; ++j) {
#pragma unroll
    for (int i = 0; i < 4; ++i) {
#pragma unroll
      for (int q = 0; q < 4; ++q) {
        float cosv = acc[i][j][q] * rn[j];
        cosv = fminf(fmaxf(cosv, -1.f), 1.f);
        float lg;
        if (lab[i][q] == cj[j]) {
          const float s = sqrtf(fmaxf(1.f - cosv * cosv, 0.f));
          lg = cosv * COS_M - s * SIN_M;
        } else {
          lg = cosv;
        }
        lg *= SCALE;
        acc[i][j][q] = lg;
        mx[j] = fmaxf(mx[j], lg);
      }
    }
  }

  // ---- softmax over the 512 rows of each column (axis=0)
#pragma unroll
  for (int j = 0; j < 4; ++j) {
    mx[j] = fmaxf(mx[j], __shfl_xor(mx[j], 16, 64));
    mx[j] = fmaxf(mx[j], __shfl_xor(mx[j], 32, 64));
  }
  if (l < 16) {
#pragma unroll
    for (int j = 0; j < 4; ++j) red[wv][j * 16 + l] = mx[j];
  }
  __syncthreads();
  if (tid < BC) {
    float m = red[0][tid];
#pragma unroll
    for (int v2 = 1; v2 < 8; ++v2) m = fmaxf(m, red[v2][tid]);
    colv[tid] = m;
  }
  __syncthreads();
  float cmax[4];
#pragma unroll
  for (int j = 0; j < 4; ++j) cmax[j] = colv[j * 16 + ll];

  float sme[4] = {0.f, 0.f, 0.f, 0.f};
#pragma unroll
  for (int j = 0; j < 4; ++j)
#pragma unroll
    for (int i = 0; i < 4; ++i)
#pragma unroll
      for (int q = 0; q < 4; ++q) {
        const float e = __expf(acc[i][j][q] - cmax[j]);
        acc[i][j][q] = e;
        sme[j] += e;
      }
#pragma unroll
  for (int j = 0; j < 4; ++j) {
    sme[j] += __shfl_xor(sme[j], 16, 64);
    sme[j] += __shfl_xor(sme[j], 32, 64);
  }
  __syncthreads();
  if (l < 16) {
#pragma unroll
    for (int j = 0; j < 4; ++j) red[wv][j * 16 + l] = sme[j];
  }
  __syncthreads();
  if (tid < BC) {
    float s = 0.f;
#pragma unroll
    for (int v2 = 0; v2 < 8; ++v2) s += red[v2][tid];
    colv[tid] = s;
  }
  __syncthreads();

  float rs[4];
#pragma unroll
  for (int j = 0; j < 4; ++j) rs[j] = 1.0f / colv[j * 16 + ll];

#pragma unroll
  for (int j = 0; j < 4; ++j) {
    if (cj[j] >= NCLS) continue;
#pragma unroll
    for (int i = 0; i < 4; ++i) {
#pragma unroll
      for (int q = 0; q < 4; ++q) {
        const int row = wv * 64 + i * 16 + lh * 4 + q;
        out[(size_t)row * NCLS + cj[j]] = acc[i][j][q] * rs[j];
      }
    }
  }
}

extern "C" void kernel_launch(void* const* d_in, const int* in_sizes, int n_in,
                              void* d_out, int out_size, void* d_ws, size_t ws_size,
                              hipStream_t stream) {
  const float* emb = (const float*)d_in[0];   // [512][512]
  const float* w   = (const float*)d_in[1];   // [512][100000]
  const float* tgt = (const float*)d_in[2];   // [512][100000]
  float* out = (float*)d_out;                 // [512][100000]

  char* ws = (char*)d_ws;
  int* labels = (int*)ws;                                   // 2 KB
  unsigned short* afrag = (unsigned short*)(ws + 4096);     // 512 KB

  label_scan<<<dim3(NROWS, 4), 1024, 0, stream>>>(tgt, labels);
  prep_afrag<<<64, 512, 0, stream>>>(emb, afrag);
  arcface_fused<<<NBLK, 512, 0, stream>>>(w, labels, afrag, out);
}

// Round 5
// 284.101 us; speedup vs baseline: 1.4583x; 1.0298x over previous
//
#include <hip/hip_runtime.h>
#include <hip/hip_bf16.h>

// ArcFace fused: cos = emb @ (w/||w||), margin at target label, softmax over batch axis.
// N=512, D=512, C=100000, S=1.
//   prep_afrag   : emb f32 -> bf16 A-fragments (512 KB, L2-resident)
//   arcface_fused: ONE pass over w AND tgt (f32, coalesced). Per block (64 cols x 512
//                  rows), pipelined K-steps with RAW barriers (no vmcnt drain):
//                  depth-2 register prefetch of w/tgt tiles, depth-1 A-frag prefetch,
//                  stage f32->LDS (+norm FMA, +label detect) -> in-LDS transpose to
//                  bf16 fragments -> ds_read_b128 + MFMA. Margin + column softmax in
//                  epilogue. Label scan is fused: tgt rows use the same addressing as
//                  w rows (N == D == 512); hits recorded in a 512B LDS byte map.

static constexpr int DIM    = 512;
static constexpr int NROWS  = 512;
static constexpr int NCLS   = 100000;
static constexpr int BC     = 64;              // columns per block
static constexpr int BK     = 32;              // K per step
static constexpr int NSTEP  = DIM / BK;        // 16
static constexpr int MT     = NROWS / 16;      // 32
static constexpr int NBLK   = (NCLS + BC - 1) / BC;  // 1563

static constexpr float COS_M = 0.87758256189037271611f;  // cos(0.5)
static constexpr float SIN_M = 0.47942553860420300027f;  // sin(0.5)
static constexpr float SCALE = 64.0f;

typedef __attribute__((ext_vector_type(8))) short bf16x8;
typedef __attribute__((ext_vector_type(4))) float f32x4;

// Raw barrier: LDS ops drained (lgkmcnt only), VMEM prefetches stay in flight.
// sched_barrier(0) pins following LDS reads below the barrier (guide rule #18).
#define SYNC_LDS()                                             \
  do {                                                         \
    asm volatile("s_waitcnt lgkmcnt(0)" ::: "memory");         \
    __builtin_amdgcn_s_barrier();                              \
    __builtin_amdgcn_sched_barrier(0);                         \
  } while (0)

__device__ __forceinline__ unsigned short f2bf(float f) {
  union { float f; unsigned u; } v; v.f = f;
  unsigned u = v.u;
  return (unsigned short)((u + 0x7FFFu + ((u >> 16) & 1u)) >> 16);
}

// ---------------------------------------------------------------------------
// emb [512][512] f32 -> bf16 A-fragments:
// afrag[((ks*MT+mt)*64 + lane)*8 + j] = bf16(emb[mt*16 + (lane&15)][ks*32 + (lane>>4)*8 + j])
// ---------------------------------------------------------------------------
__global__ void prep_afrag(const float* __restrict__ emb,
                           unsigned short* __restrict__ afrag) {
  const int idx = blockIdx.x * blockDim.x + threadIdx.x;  // 0..32767
  const int l  = idx & 63;
  const int mt = (idx >> 6) & 31;
  const int ks = idx >> 11;
  const int row = mt * 16 + (l & 15);
  const int k0  = ks * 32 + (l >> 4) * 8;

  unsigned short t[8];
#pragma unroll
  for (int j = 0; j < 8; ++j) t[j] = f2bf(emb[row * DIM + k0 + j]);

  uint4 v;
  v.x = (unsigned)t[0] | ((unsigned)t[1] << 16);
  v.y = (unsigned)t[2] | ((unsigned)t[3] << 16);
  v.z = (unsigned)t[4] | ((unsigned)t[5] << 16);
  v.w = (unsigned)t[6] | ((unsigned)t[7] << 16);
  *reinterpret_cast<uint4*>(&afrag[(size_t)idx * 8]) = v;
}

// guarded float4 load of m[r][cg..cg+3] for a [*][NCLS] row-major matrix
__device__ __forceinline__ float4 ldr4(const float* __restrict__ m, int r, int cg) {
  if (cg + 3 < NCLS)
    return *reinterpret_cast<const float4*>(m + (size_t)r * NCLS + cg);
  float4 v = {0.f, 0.f, 0.f, 0.f};
  const size_t rb = (size_t)r * NCLS;
  if (cg + 0 < NCLS) v.x = m[rb + cg + 0];
  if (cg + 1 < NCLS) v.y = m[rb + cg + 1];
  if (cg + 2 < NCLS) v.z = m[rb + cg + 2];
  if (cg + 3 < NCLS) v.w = m[rb + cg + 3];
  return v;
}

// ---------------------------------------------------------------------------
// Main fused kernel. 512 threads = 8 waves. Wave wv owns rows [wv*64, wv*64+64).
// ---------------------------------------------------------------------------
__global__ __launch_bounds__(512)
void arcface_fused(const float* __restrict__ w,
                   const float* __restrict__ tgt,
                   const unsigned short* __restrict__ afrag,
                   float* __restrict__ out) {
  __shared__ float S1[BK][68];                      // staged f32 tile (pad 68)
  __shared__ alignas(16) unsigned short S2[256][8]; // bf16 fragments [lh*64+c][e]
  __shared__ float red[8][BC];
  __shared__ float colv[BC];
  __shared__ float rnS[BC];
  __shared__ unsigned char labL[NROWS];             // local col+1 of row's label, else 0

  const int tid = threadIdx.x;
  const int wv  = tid >> 6;
  const int l   = tid & 63;
  const int lh  = l >> 4;
  const int ll  = l & 15;
  const int c0  = blockIdx.x * BC;

  // staging role: thread stages k-row sk, cols scg..scg+3
  const int sk  = tid >> 4;        // 0..31
  const int sc4 = tid & 15;
  const int scg = c0 + sc4 * 4;

  // init label map, make visible before any stage-phase writes/epilogue reads
  if (tid < 128) *reinterpret_cast<unsigned*>(&labL[tid * 4]) = 0u;
  __syncthreads();

  int cj[4];
#pragma unroll
  for (int j = 0; j < 4; ++j) cj[j] = c0 + j * 16 + ll;

  const unsigned short* pA[4];
#pragma unroll
  for (int i = 0; i < 4; ++i)
    pA[i] = afrag + ((size_t)(wv * 4 + i) * 64 + l) * 8;

  f32x4 acc[4][4] = {};
  float4 nrm4 = {0.f, 0.f, 0.f, 0.f};

  // prologue: A-frags for step 0; w/tgt tiles for steps 0 and 1 (depth-2 pipeline)
  bf16x8 a[4], an[4];
#pragma unroll
  for (int i = 0; i < 4; ++i) {
    a[i]  = *reinterpret_cast<const bf16x8*>(pA[i]);
    an[i] = a[i];
  }
  float4 v0 = ldr4(w,   sk,      scg);
  float4 t0 = ldr4(tgt, sk,      scg);
  float4 v1 = ldr4(w,   BK + sk, scg);
  float4 t1 = ldr4(tgt, BK + sk, scg);

  for (int ks = 0; ks < NSTEP; ++ks) {
    // ---- phase S: consume v0/t0 (compiler emits counted vmcnt; newer prefetches fly)
    nrm4.x += v0.x * v0.x; nrm4.y += v0.y * v0.y;
    nrm4.z += v0.z * v0.z; nrm4.w += v0.w * v0.w;
    *reinterpret_cast<float4*>(&S1[sk][sc4 * 4]) = v0;

    // label detect: tgt row ks*32+sk, cols scg..scg+3 (one-hot -> at most one writer)
    {
      const int row = ks * BK + sk;
      if (t0.x > 0.5f) labL[row] = (unsigned char)(sc4 * 4 + 1);
      if (t0.y > 0.5f) labL[row] = (unsigned char)(sc4 * 4 + 2);
      if (t0.z > 0.5f) labL[row] = (unsigned char)(sc4 * 4 + 3);
      if (t0.w > 0.5f) labL[row] = (unsigned char)(sc4 * 4 + 4);
    }
    v0 = v1; t0 = t1;

    // issue A-frag prefetch (ks+1) BEFORE the next w/tgt loads: the vmcnt wait for
    // a[] at next MFMA then leaves the (newer) w/tgt prefetch in flight.
    if (ks + 1 < NSTEP) {
#pragma unroll
      for (int i = 0; i < 4; ++i)
        an[i] = *reinterpret_cast<const bf16x8*>(pA[i] + (size_t)(ks + 1) * MT * 64 * 8);
    }
    if (ks + 2 < NSTEP) {
      v1 = ldr4(w,   (ks + 2) * BK + sk, scg);
      t1 = ldr4(tgt, (ks + 2) * BK + sk, scg);
    }

    SYNC_LDS();   // stage writes visible; w/tgt/a prefetches remain outstanding

    // ---- phase T: transpose 32x64 f32 -> bf16 fragment layout (first 4 waves)
    if (tid < 256) {
      const int tc = tid & 63;    // column
      const int tl = tid >> 6;    // k-group 0..3
      float x[8];
#pragma unroll
      for (int e = 0; e < 8; ++e) x[e] = S1[tl * 8 + e][tc];
      uint4 pk;
      pk.x = (unsigned)f2bf(x[0]) | ((unsigned)f2bf(x[1]) << 16);
      pk.y = (unsigned)f2bf(x[2]) | ((unsigned)f2bf(x[3]) << 16);
      pk.z = (unsigned)f2bf(x[4]) | ((unsigned)f2bf(x[5]) << 16);
      pk.w = (unsigned)f2bf(x[6]) | ((unsigned)f2bf(x[7]) << 16);
      *reinterpret_cast<uint4*>(&S2[tl * 64 + tc][0]) = pk;
    }

    SYNC_LDS();

    // ---- phase M: B fragments from LDS + MFMA
    bf16x8 b[4];
#pragma unroll
    for (int j = 0; j < 4; ++j)
      b[j] = *reinterpret_cast<const bf16x8*>(&S2[lh * 64 + j * 16 + ll][0]);
#pragma unroll
    for (int i = 0; i < 4; ++i)
#pragma unroll
      for (int j = 0; j < 4; ++j)
        acc[i][j] = __builtin_amdgcn_mfma_f32_16x16x32_bf16(a[i], b[j], acc[i][j], 0, 0, 0);
#pragma unroll
    for (int i = 0; i < 4; ++i) a[i] = an[i];
  }

  // ---- finish column norms: reuse S1 for partials
  __syncthreads();
  *reinterpret_cast<float4*>(&S1[sk][sc4 * 4]) = nrm4;
  __syncthreads();
  if (tid < BC) {
    float s = 0.f;
#pragma unroll
    for (int k = 0; k < BK; ++k) s += S1[k][tid];
    rnS[tid] = rsqrtf(fmaxf(s, 1e-20f));
  }
  __syncthreads();
  float rn[4];
#pragma unroll
  for (int j = 0; j < 4; ++j) rn[j] = rnS[j * 16 + ll];

  // ---- labels for my 16 rows from the LDS byte map
  int lab[4][4];
#pragma unroll
  for (int i = 0; i < 4; ++i)
#pragma unroll
    for (int q = 0; q < 4; ++q)
      lab[i][q] = (int)labL[wv * 64 + i * 16 + lh * 4 + q] - 1;  // local col or -1

  // ---- logits: cos*rn -> clip -> margin at target -> *64; track col max
  float mx[4];
#pragma unroll
  for (int j = 0; j < 4; ++j) mx[j] = -3.4e38f;
#pragma unroll
  for (int j = 0; j < 4; ++j) {
    const int jl = j * 16 + ll;   // local column index
#pragma unroll
    for (int i = 0; i < 4; ++i) {
#pragma unroll
      for (int q = 0; q < 4; ++q) {
        float cosv = acc[i][j][q] * rn[j];
        cosv = fminf(fmaxf(cosv, -1.f), 1.f);
        float lg;
        if (lab[i][q] == jl) {
          const float s = sqrtf(fmaxf(1.f - cosv * cosv, 0.f));
          lg = cosv * COS_M - s * SIN_M;
        } else {
          lg = cosv;
        }
        lg *= SCALE;
        acc[i][j][q] = lg;
        mx[j] = fmaxf(mx[j], lg);
      }
    }
  }

  // ---- softmax over the 512 rows of each column (axis=0)
#pragma unroll
  for (int j = 0; j < 4; ++j) {
    mx[j] = fmaxf(mx[j], __shfl_xor(mx[j], 16, 64));
    mx[j] = fmaxf(mx[j], __shfl_xor(mx[j], 32, 64));
  }
  if (l < 16) {
#pragma unroll
    for (int j = 0; j < 4; ++j) red[wv][j * 16 + l] = mx[j];
  }
  __syncthreads();
  if (tid < BC) {
    float m = red[0][tid];
#pragma unroll
    for (int v2 = 1; v2 < 8; ++v2) m = fmaxf(m, red[v2][tid]);
    colv[tid] = m;
  }
  __syncthreads();
  float cmax[4];
#pragma unroll
  for (int j = 0; j < 4; ++j) cmax[j] = colv[j * 16 + ll];

  float sme[4] = {0.f, 0.f, 0.f, 0.f};
#pragma unroll
  for (int j = 0; j < 4; ++j)
#pragma unroll
    for (int i = 0; i < 4; ++i)
#pragma unroll
      for (int q = 0; q < 4; ++q) {
        const float e = __expf(acc[i][j][q] - cmax[j]);
        acc[i][j][q] = e;
        sme[j] += e;
      }
#pragma unroll
  for (int j = 0; j < 4; ++j) {
    sme[j] += __shfl_xor(sme[j], 16, 64);
    sme[j] += __shfl_xor(sme[j], 32, 64);
  }
  __syncthreads();
  if (l < 16) {
#pragma unroll
    for (int j = 0; j < 4; ++j) red[wv][j * 16 + l] = sme[j];
  }
  __syncthreads();
  if (tid < BC) {
    float s = 0.f;
#pragma unroll
    for (int v2 = 0; v2 < 8; ++v2) s += red[v2][tid];
    colv[tid] = s;
  }
  __syncthreads();

  float rs[4];
#pragma unroll
  for (int j = 0; j < 4; ++j) rs[j] = 1.0f / colv[j * 16 + ll];

#pragma unroll
  for (int j = 0; j < 4; ++j) {
    if (cj[j] >= NCLS) continue;
#pragma unroll
    for (int i = 0; i < 4; ++i) {
#pragma unroll
      for (int q = 0; q < 4; ++q) {
        const int row = wv * 64 + i * 16 + lh * 4 + q;
        out[(size_t)row * NCLS + cj[j]] = acc[i][j][q] * rs[j];
      }
    }
  }
}

extern "C" void kernel_launch(void* const* d_in, const int* in_sizes, int n_in,
                              void* d_out, int out_size, void* d_ws, size_t ws_size,
                              hipStream_t stream) {
  const float* emb = (const float*)d_in[0];   // [512][512]
  const float* w   = (const float*)d_in[1];   // [512][100000]
  const float* tgt = (const float*)d_in[2];   // [512][100000]
  float* out = (float*)d_out;                 // [512][100000]

  char* ws = (char*)d_ws;
  unsigned short* afrag = (unsigned short*)(ws + 4096);     // 512 KB

  prep_afrag<<<64, 512, 0, stream>>>(emb, afrag);
  arcface_fused<<<NBLK, 512, 0, stream>>>(w, tgt, afrag, out);
}

// Round 6
// 231.150 us; speedup vs baseline: 1.7923x; 1.2291x over previous
//
#include <hip/hip_runtime.h>
#include <hip/hip_bf16.h>

// ArcFace fused: cos = emb @ (w/||w||), margin at target label, softmax over batch axis.
// N=512, D=512, C=100000, S=1.
//   prep_afrag   : emb f32 -> bf16 A-fragments (512 KB, L2-resident)
//   arcface_fused: ONE pass over w AND tgt (f32, coalesced). Per block: 32 cols x all
//                  512 rows (100000 = 32*3125 -> no edge guards). 8 waves; wave owns
//                  64 rows x 32 cols -> acc[4][2] = 32 AGPR; __launch_bounds__(512,4)
//                  caps regs at 128 -> 2 blocks/CU resident (the round-6 lever: rounds
//                  2-5 all sat at 1 block/CU, 2 waves/SIMD, >90% stall).
//                  Pipelined K-steps: depth-2 reg prefetch of w/tgt float2, depth-1
//                  A-frag prefetch, raw lgkmcnt-only barriers (VMEM stays in flight),
//                  stage f32->LDS (+norm FMA, +one-hot label detect) -> in-LDS
//                  transpose to bf16 fragments -> ds_read_b128 + MFMA.
//                  Margin + in-block column softmax in epilogue.

static constexpr int DIM    = 512;
static constexpr int NROWS  = 512;
static constexpr int NCLS   = 100000;
static constexpr int BC     = 32;              // columns per block
static constexpr int BK     = 32;              // K per step
static constexpr int NSTEP  = DIM / BK;        // 16
static constexpr int MT     = NROWS / 16;      // 32
static constexpr int NBLK   = NCLS / BC;       // 3125 (exact)

static constexpr float COS_M = 0.87758256189037271611f;  // cos(0.5)
static constexpr float SIN_M = 0.47942553860420300027f;  // sin(0.5)
static constexpr float SCALE = 64.0f;

typedef __attribute__((ext_vector_type(8))) short bf16x8;
typedef __attribute__((ext_vector_type(4))) float f32x4;

// Raw barrier: LDS ops drained (lgkmcnt only), VMEM prefetches stay in flight.
// sched_barrier(0) pins following LDS ops below the barrier (guide rule #18).
#define SYNC_LDS()                                             \
  do {                                                         \
    asm volatile("s_waitcnt lgkmcnt(0)" ::: "memory");         \
    __builtin_amdgcn_s_barrier();                              \
    __builtin_amdgcn_sched_barrier(0);                         \
  } while (0)

__device__ __forceinline__ unsigned short f2bf(float f) {
  union { float f; unsigned u; } v; v.f = f;
  unsigned u = v.u;
  return (unsigned short)((u + 0x7FFFu + ((u >> 16) & 1u)) >> 16);
}

// ---------------------------------------------------------------------------
// emb [512][512] f32 -> bf16 A-fragments:
// afrag[((ks*MT+mt)*64 + lane)*8 + j] = bf16(emb[mt*16 + (lane&15)][ks*32 + (lane>>4)*8 + j])
// ---------------------------------------------------------------------------
__global__ void prep_afrag(const float* __restrict__ emb,
                           unsigned short* __restrict__ afrag) {
  const int idx = blockIdx.x * blockDim.x + threadIdx.x;  // 0..32767
  const int l  = idx & 63;
  const int mt = (idx >> 6) & 31;
  const int ks = idx >> 11;
  const int row = mt * 16 + (l & 15);
  const int k0  = ks * 32 + (l >> 4) * 8;

  unsigned short t[8];
#pragma unroll
  for (int j = 0; j < 8; ++j) t[j] = f2bf(emb[row * DIM + k0 + j]);

  uint4 v;
  v.x = (unsigned)t[0] | ((unsigned)t[1] << 16);
  v.y = (unsigned)t[2] | ((unsigned)t[3] << 16);
  v.z = (unsigned)t[4] | ((unsigned)t[5] << 16);
  v.w = (unsigned)t[6] | ((unsigned)t[7] << 16);
  *reinterpret_cast<uint4*>(&afrag[(size_t)idx * 8]) = v;
}

// unguarded float2 load of m[r][c..c+1] for a [*][NCLS] row-major matrix
__device__ __forceinline__ float2 ldr2(const float* __restrict__ m, int r, int c) {
  return *reinterpret_cast<const float2*>(m + (size_t)r * NCLS + c);
}

// ---------------------------------------------------------------------------
// Main fused kernel. 512 threads = 8 waves, 2 blocks/CU.
// Wave wv owns rows [wv*64, wv*64+64) x the block's 32 columns.
// ---------------------------------------------------------------------------
__global__ __launch_bounds__(512, 4)
void arcface_fused(const float* __restrict__ w,
                   const float* __restrict__ tgt,
                   const unsigned short* __restrict__ afrag,
                   float* __restrict__ out) {
  __shared__ float S1[BK][36];                      // staged f32 tile (pad 36)
  __shared__ alignas(16) unsigned short S2[128][8]; // bf16 frags [kgrp*32+c][e]
  __shared__ float red[8][BC];
  __shared__ float colv[BC];
  __shared__ float rnS[BC];
  __shared__ unsigned char labL[NROWS];             // local col+1 of row's label, else 0

  const int tid = threadIdx.x;
  const int wv  = tid >> 6;
  const int l   = tid & 63;
  const int lh  = l >> 4;
  const int ll  = l & 15;
  const int c0  = blockIdx.x * BC;

  // staging role: thread stages k-row sk, cols scg..scg+1 (float2)
  const int sk  = tid >> 4;        // 0..31
  const int sc2 = tid & 15;
  const int scg = c0 + sc2 * 2;

  // init label map; visible before any stage-phase writes / epilogue reads
  if (tid < 128) *reinterpret_cast<unsigned*>(&labL[tid * 4]) = 0u;
  __syncthreads();

  int cj[2];
#pragma unroll
  for (int j = 0; j < 2; ++j) cj[j] = c0 + j * 16 + ll;

  const unsigned short* pA[4];
#pragma unroll
  for (int i = 0; i < 4; ++i)
    pA[i] = afrag + ((size_t)(wv * 4 + i) * 64 + l) * 8;

  f32x4 acc[4][2] = {};
  float nx = 0.f, ny = 0.f;

  // prologue: A-frags for step 0; w/tgt tiles for steps 0 and 1 (depth-2 pipeline)
  bf16x8 a[4], an[4];
#pragma unroll
  for (int i = 0; i < 4; ++i) {
    a[i]  = *reinterpret_cast<const bf16x8*>(pA[i]);
    an[i] = a[i];
  }
  float2 v0 = ldr2(w,   sk,      scg);
  float2 t0 = ldr2(tgt, sk,      scg);
  float2 v1 = ldr2(w,   BK + sk, scg);
  float2 t1 = ldr2(tgt, BK + sk, scg);

  for (int ks = 0; ks < NSTEP; ++ks) {
    // ---- phase S: consume v0/t0 (counted vmcnt; newer prefetches stay in flight)
    nx += v0.x * v0.x; ny += v0.y * v0.y;
    *reinterpret_cast<float2*>(&S1[sk][sc2 * 2]) = v0;

    // one-hot label detect: tgt row ks*32+sk, cols scg..scg+1 (at most one writer)
    {
      const int row = ks * BK + sk;
      if (t0.x > 0.5f) labL[row] = (unsigned char)(sc2 * 2 + 1);
      if (t0.y > 0.5f) labL[row] = (unsigned char)(sc2 * 2 + 2);
    }
    v0 = v1; t0 = t1;

    // A-frag prefetch (ks+1) issued BEFORE next w/tgt loads so its vmcnt wait
    // leaves the (newer) w/tgt prefetch outstanding.
    if (ks + 1 < NSTEP) {
#pragma unroll
      for (int i = 0; i < 4; ++i)
        an[i] = *reinterpret_cast<const bf16x8*>(pA[i] + (size_t)(ks + 1) * MT * 64 * 8);
    }
    if (ks + 2 < NSTEP) {
      v1 = ldr2(w,   (ks + 2) * BK + sk, scg);
      t1 = ldr2(tgt, (ks + 2) * BK + sk, scg);
    }

    SYNC_LDS();   // stage writes visible; w/tgt/a prefetches remain outstanding

    // ---- phase T: transpose 32x32 f32 -> bf16 fragment layout (waves 0-3)
    if (tid < 256) {
      const int tc = tid & 31;          // column
      const int tl = (tid >> 5) & 3;    // k-octet
      const int hf = (tid >> 7) & 1;    // half of the octet
      const int kb = tl * 8 + hf * 4;
      float x0 = S1[kb + 0][tc], x1 = S1[kb + 1][tc];
      float x2 = S1[kb + 2][tc], x3 = S1[kb + 3][tc];
      uint2 pk;
      pk.x = (unsigned)f2bf(x0) | ((unsigned)f2bf(x1) << 16);
      pk.y = (unsigned)f2bf(x2) | ((unsigned)f2bf(x3) << 16);
      *reinterpret_cast<uint2*>(&S2[tl * 32 + tc][hf * 4]) = pk;
    }

    SYNC_LDS();

    // ---- phase M: B fragments from LDS + MFMA
    bf16x8 b[2];
#pragma unroll
    for (int j = 0; j < 2; ++j)
      b[j] = *reinterpret_cast<const bf16x8*>(&S2[lh * 32 + j * 16 + ll][0]);
#pragma unroll
    for (int i = 0; i < 4; ++i)
#pragma unroll
      for (int j = 0; j < 2; ++j)
        acc[i][j] = __builtin_amdgcn_mfma_f32_16x16x32_bf16(a[i], b[j], acc[i][j], 0, 0, 0);
#pragma unroll
    for (int i = 0; i < 4; ++i) a[i] = an[i];
  }

  // ---- finish column norms: reuse S1 for partials
  __syncthreads();
  *reinterpret_cast<float2*>(&S1[sk][sc2 * 2]) = make_float2(nx, ny);
  __syncthreads();
  if (tid < BC) {
    float s = 0.f;
#pragma unroll
    for (int k = 0; k < BK; ++k) s += S1[k][tid];
    rnS[tid] = rsqrtf(fmaxf(s, 1e-20f));
  }
  __syncthreads();
  float rn[2];
#pragma unroll
  for (int j = 0; j < 2; ++j) rn[j] = rnS[j * 16 + ll];

  // ---- labels for my 16 rows from the LDS byte map
  int lab[4][4];
#pragma unroll
  for (int i = 0; i < 4; ++i)
#pragma unroll
    for (int q = 0; q < 4; ++q)
      lab[i][q] = (int)labL[wv * 64 + i * 16 + lh * 4 + q] - 1;  // local col or -1

  // ---- logits: cos*rn -> clip -> margin at target -> *64; track col max
  float mx[2] = {-3.4e38f, -3.4e38f};
#pragma unroll
  for (int j = 0; j < 2; ++j) {
    const int jl = j * 16 + ll;   // local column index
#pragma unroll
    for (int i = 0; i < 4; ++i) {
#pragma unroll
      for (int q = 0; q < 4; ++q) {
        float cosv = acc[i][j][q] * rn[j];
        cosv = fminf(fmaxf(cosv, -1.f), 1.f);
        float lg;
        if (lab[i][q] == jl) {
          const float s = sqrtf(fmaxf(1.f - cosv * cosv, 0.f));
          lg = cosv * COS_M - s * SIN_M;
        } else {
          lg = cosv;
        }
        lg *= SCALE;
        acc[i][j][q] = lg;
        mx[j] = fmaxf(mx[j], lg);
      }
    }
  }

  // ---- softmax over the 512 rows of each column (axis=0)
#pragma unroll
  for (int j = 0; j < 2; ++j) {
    mx[j] = fmaxf(mx[j], __shfl_xor(mx[j], 16, 64));
    mx[j] = fmaxf(mx[j], __shfl_xor(mx[j], 32, 64));
  }
  if (l < 16) {
#pragma unroll
    for (int j = 0; j < 2; ++j) red[wv][j * 16 + l] = mx[j];
  }
  __syncthreads();
  if (tid < BC) {
    float m = red[0][tid];
#pragma unroll
    for (int v2 = 1; v2 < 8; ++v2) m = fmaxf(m, red[v2][tid]);
    colv[tid] = m;
  }
  __syncthreads();
  float cmax[2];
#pragma unroll
  for (int j = 0; j < 2; ++j) cmax[j] = colv[j * 16 + ll];

  float sme[2] = {0.f, 0.f};
#pragma unroll
  for (int j = 0; j < 2; ++j)
#pragma unroll
    for (int i = 0; i < 4; ++i)
#pragma unroll
      for (int q = 0; q < 4; ++q) {
        const float e = __expf(acc[i][j][q] - cmax[j]);
        acc[i][j][q] = e;
        sme[j] += e;
      }
#pragma unroll
  for (int j = 0; j < 2; ++j) {
    sme[j] += __shfl_xor(sme[j], 16, 64);
    sme[j] += __shfl_xor(sme[j], 32, 64);
  }
  __syncthreads();
  if (l < 16) {
#pragma unroll
    for (int j = 0; j < 2; ++j) red[wv][j * 16 + l] = sme[j];
  }
  __syncthreads();
  if (tid < BC) {
    float s = 0.f;
#pragma unroll
    for (int v2 = 0; v2 < 8; ++v2) s += red[v2][tid];
    colv[tid] = s;
  }
  __syncthreads();

  float rs[2];
#pragma unroll
  for (int j = 0; j < 2; ++j) rs[j] = 1.0f / colv[j * 16 + ll];

#pragma unroll
  for (int j = 0; j < 2; ++j) {
#pragma unroll
    for (int i = 0; i < 4; ++i) {
#pragma unroll
      for (int q = 0; q < 4; ++q) {
        const int row = wv * 64 + i * 16 + lh * 4 + q;
        out[(size_t)row * NCLS + cj[j]] = acc[i][j][q] * rs[j];
      }
    }
  }
}

extern "C" void kernel_launch(void* const* d_in, const int* in_sizes, int n_in,
                              void* d_out, int out_size, void* d_ws, size_t ws_size,
                              hipStream_t stream) {
  const float* emb = (const float*)d_in[0];   // [512][512]
  const float* w   = (const float*)d_in[1];   // [512][100000]
  const float* tgt = (const float*)d_in[2];   // [512][100000]
  float* out = (float*)d_out;                 // [512][100000]

  char* ws = (char*)d_ws;
  unsigned short* afrag = (unsigned short*)(ws + 4096);     // 512 KB

  prep_afrag<<<64, 512, 0, stream>>>(emb, afrag);
  arcface_fused<<<NBLK, 512, 0, stream>>>(w, tgt, afrag, out);
}

// Round 7
// 225.657 us; speedup vs baseline: 1.8359x; 1.0243x over previous
//
#include <hip/hip_runtime.h>
#include <hip/hip_bf16.h>

// ArcFace fused: cos = emb @ (w/||w||), margin at target label, softmax over batch axis.
// N=512, D=512, C=100000, S=1.
//   prep_afrag   : emb f32 -> bf16 A-fragments (512 KB, L2-resident)
//   arcface_fused: ONE pass over w AND tgt. Per block: 32 cols x 512 rows.
//     Round-7 structure (kill per-step drains):
//       - w tile staged by global_load_lds DMA (f32, S1 triple-buffer, issued 2 steps
//         ahead) -- no VALU, no reg round-trip.
//       - ONE lgkm-only barrier per step; VMEM stays in flight across it.
//       - 16 hand-instantiated STEP macros: literal buffer indices, no reg copies
//         (copies force compiler vmcnt drains -- the round 4-6 hidden stall).
//       - manual counted vmcnt literals (5/9/8) from exact per-wave VMEM order;
//         each wave transposes only rows it DMA'd (per-wave vmcnt is sufficient).
//       - role-split: waves 0-3 stage+transpose+norm; waves 4-7 tgt one-hot scan;
//         all 8 waves MFMA, setprio(1) around the MFMA cluster.

static constexpr int DIM    = 512;
static constexpr int NROWS  = 512;
static constexpr int NCLS   = 100000;
static constexpr int BC     = 32;              // columns per block
static constexpr int BK     = 32;              // K per step
static constexpr int NSTEP  = DIM / BK;        // 16
static constexpr int MT     = NROWS / 16;      // 32
static constexpr int NBLK   = NCLS / BC;       // 3125 exact

static constexpr float COS_M = 0.87758256189037271611f;  // cos(0.5)
static constexpr float SIN_M = 0.47942553860420300027f;  // sin(0.5)
static constexpr float SCALE = 64.0f;

typedef __attribute__((ext_vector_type(8))) short bf16x8;
typedef __attribute__((ext_vector_type(4))) float f32x4;

#define MFMA16(A, B, C) __builtin_amdgcn_mfma_f32_16x16x32_bf16((A), (B), (C), 0, 0, 0)

__device__ __forceinline__ unsigned short f2bf(float f) {
  union { float f; unsigned u; } v; v.f = f;
  unsigned u = v.u;
  return (unsigned short)((u + 0x7FFFu + ((u >> 16) & 1u)) >> 16);
}

// ---------------------------------------------------------------------------
// emb [512][512] f32 -> bf16 A-fragments:
// afrag[((ks*MT+mt)*64 + lane)*8 + j] = bf16(emb[mt*16 + (lane&15)][ks*32 + (lane>>4)*8 + j])
// ---------------------------------------------------------------------------
__global__ void prep_afrag(const float* __restrict__ emb,
                           unsigned short* __restrict__ afrag) {
  const int idx = blockIdx.x * blockDim.x + threadIdx.x;  // 0..32767
  const int l  = idx & 63;
  const int mt = (idx >> 6) & 31;
  const int ks = idx >> 11;
  const int row = mt * 16 + (l & 15);
  const int k0  = ks * 32 + (l >> 4) * 8;

  unsigned short t[8];
#pragma unroll
  for (int j = 0; j < 8; ++j) t[j] = f2bf(emb[row * DIM + k0 + j]);

  uint4 v;
  v.x = (unsigned)t[0] | ((unsigned)t[1] << 16);
  v.y = (unsigned)t[2] | ((unsigned)t[3] << 16);
  v.z = (unsigned)t[4] | ((unsigned)t[5] << 16);
  v.w = (unsigned)t[6] | ((unsigned)t[7] << 16);
  *reinterpret_cast<uint4*>(&afrag[(size_t)idx * 8]) = v;
}

// DMA one eighth-tile: wave wv stages rows [ks*32+wv*8, +8) x 32 cols into
// S1[buf] at byte offset buf*4096 + wv*1024 (linear [32][32] f32 layout).
__device__ __forceinline__ void stage_tile(const float* __restrict__ w, int c0,
                                           int ks, int wv, int l,
                                           char* s1base, int buf) {
  const float* g = w + (size_t)(ks * BK + wv * 8 + (l >> 3)) * NCLS
                     + (c0 + (l & 7) * 4);
  const int off = __builtin_amdgcn_readfirstlane(buf * 4096 + wv * 1024);
  __builtin_amdgcn_global_load_lds(
      (const __attribute__((address_space(1))) void*)g,
      (__attribute__((address_space(3))) void*)(s1base + off),
      16, 0, 0);
}

// ---------------------------------------------------------------------------
// Main fused kernel. 512 threads = 8 waves, 2 blocks/CU.
// ---------------------------------------------------------------------------
__global__ __launch_bounds__(512, 4)
void arcface_fused(const float* __restrict__ w,
                   const float* __restrict__ tgt,
                   const unsigned short* __restrict__ afrag,
                   float* __restrict__ out) {
  __shared__ float S1[3][BK][BC];                      // 12 KB, DMA-staged f32 tiles
  __shared__ alignas(16) unsigned short S2[2][128][8]; // 4 KB, bf16 fragments
  __shared__ float nrmP[8][BC];
  __shared__ float red[8][BC];
  __shared__ float colv[BC];
  __shared__ float rnS[BC];
  __shared__ unsigned char labL[NROWS];

  const int tid = threadIdx.x;
  const int wv  = tid >> 6;
  const int l   = tid & 63;
  const int lh  = l >> 4;
  const int ll  = l & 15;
  const int c0  = blockIdx.x * BC;

  // transpose role (tid < 256): col tc, k-quad tq (4 k's)
  const int tc = tid & 31;
  const int tq = (tid >> 5) & 7;
  // tgt role (tid >= 256): row tr, col group tcc
  const int tid2 = tid & 255;
  const int tr   = tid2 >> 3;
  const int tcc  = (tid2 & 7) * 4;

  if (tid < 128) reinterpret_cast<unsigned*>(labL)[tid] = 0u;
  __syncthreads();   // before any VMEM issue (this one may drain; loop ones don't)

  const unsigned short* pA[4];
#pragma unroll
  for (int i = 0; i < 4; ++i)
    pA[i] = afrag + ((size_t)(wv * 4 + i) * 64 + l) * 8;

  f32x4 acc[4][2] = {};
  float nrm = 0.f;
  bf16x8 areg[2][4];
  float4 treg[2];
  char* s1base = (char*)&S1[0][0][0];

  // ---- prologue: VMEM order (stager waves): gl_lds(0), gl_lds(1), afrag(0)x4
  if (wv < 4) {
    stage_tile(w, c0, 0, wv, l, s1base, 0);
    stage_tile(w, c0, 1, wv, l, s1base, 1);
  }
  __builtin_amdgcn_sched_barrier(0);
#pragma unroll
  for (int i = 0; i < 4; ++i)
    areg[0][i] = *reinterpret_cast<const bf16x8*>(pA[i]);
  __builtin_amdgcn_sched_barrier(0);
  if (wv >= 4) {
    treg[0] = *reinterpret_cast<const float4*>(tgt + (size_t)(0 * BK + tr) * NCLS + c0 + tcc);
    treg[1] = *reinterpret_cast<const float4*>(tgt + (size_t)(1 * BK + tr) * NCLS + c0 + tcc);
  }

  // Per-step: [vmcnt][stage KS+2][transpose S1[KS%3] -> S2[KS&1], norm] |
  //           [labels from treg, load treg KS+2]  then ONE barrier, afrag(KS+1),
  //           MFMA from S2[KS&1] with areg[KS&1].
  // vmcnt literals (stager-wave queue = gl_lds + 4x afrag only):
  //   step 0: outstanding gl0,gl1,af0x4 -> newer than gl0 = 5
  //   steps 1-14: newer than gl(K) = af(K-1)x4 + gl(K+1) + af(K)x4 = 9
  //   step 15: newer than gl15 = af14x4 + af15x4 = 8
#define STEP(KS, VM)                                                            \
  {                                                                             \
    if (wv < 4) {                                                               \
      asm volatile("s_waitcnt vmcnt(" #VM ")" ::: "memory");                    \
      __builtin_amdgcn_sched_barrier(0);                                        \
      if ((KS) + 2 < NSTEP)                                                     \
        stage_tile(w, c0, (KS) + 2, wv, l, s1base, ((KS) + 2) % 3);             \
      __builtin_amdgcn_sched_barrier(0);                                        \
      const float x0 = S1[(KS) % 3][tq * 4 + 0][tc];                            \
      const float x1 = S1[(KS) % 3][tq * 4 + 1][tc];                            \
      const float x2 = S1[(KS) % 3][tq * 4 + 2][tc];                            \
      const float x3 = S1[(KS) % 3][tq * 4 + 3][tc];                            \
      nrm += x0 * x0 + x1 * x1 + x2 * x2 + x3 * x3;                             \
      uint2 pk2;                                                                \
      pk2.x = (unsigned)f2bf(x0) | ((unsigned)f2bf(x1) << 16);                  \
      pk2.y = (unsigned)f2bf(x2) | ((unsigned)f2bf(x3) << 16);                  \
      *reinterpret_cast<uint2*>(&S2[(KS) & 1][(tq >> 1) * 32 + tc][(tq & 1) * 4]) = pk2; \
    } else {                                                                    \
      const float4 tv = treg[(KS) & 1];                                         \
      const int trow = (KS) * BK + tr;                                          \
      if (tv.x > 0.5f) labL[trow] = (unsigned char)(tcc + 1);                   \
      if (tv.y > 0.5f) labL[trow] = (unsigned char)(tcc + 2);                   \
      if (tv.z > 0.5f) labL[trow] = (unsigned char)(tcc + 3);                   \
      if (tv.w > 0.5f) labL[trow] = (unsigned char)(tcc + 4);                   \
      if ((KS) + 2 < NSTEP)                                                     \
        treg[(KS) & 1] = *reinterpret_cast<const float4*>(                      \
            tgt + (size_t)(((KS) + 2) * BK + tr) * NCLS + c0 + tcc);            \
    }                                                                           \
    asm volatile("s_waitcnt lgkmcnt(0)" ::: "memory");                          \
    __builtin_amdgcn_s_barrier();                                               \
    __builtin_amdgcn_sched_barrier(0);                                          \
    if ((KS) + 1 < NSTEP) {                                                     \
      areg[((KS) + 1) & 1][0] = *reinterpret_cast<const bf16x8*>(pA[0] + (size_t)((KS) + 1) * MT * 64 * 8); \
      areg[((KS) + 1) & 1][1] = *reinterpret_cast<const bf16x8*>(pA[1] + (size_t)((KS) + 1) * MT * 64 * 8); \
      areg[((KS) + 1) & 1][2] = *reinterpret_cast<const bf16x8*>(pA[2] + (size_t)((KS) + 1) * MT * 64 * 8); \
      areg[((KS) + 1) & 1][3] = *reinterpret_cast<const bf16x8*>(pA[3] + (size_t)((KS) + 1) * MT * 64 * 8); \
    }                                                                           \
    __builtin_amdgcn_sched_barrier(0);                                          \
    __builtin_amdgcn_s_setprio(1);                                              \
    {                                                                           \
      const bf16x8 b0 = *reinterpret_cast<const bf16x8*>(&S2[(KS) & 1][lh * 32 + ll][0]);      \
      const bf16x8 b1 = *reinterpret_cast<const bf16x8*>(&S2[(KS) & 1][lh * 32 + 16 + ll][0]); \
      acc[0][0] = MFMA16(areg[(KS) & 1][0], b0, acc[0][0]);                     \
      acc[0][1] = MFMA16(areg[(KS) & 1][0], b1, acc[0][1]);                     \
      acc[1][0] = MFMA16(areg[(KS) & 1][1], b0, acc[1][0]);                     \
      acc[1][1] = MFMA16(areg[(KS) & 1][1], b1, acc[1][1]);                     \
      acc[2][0] = MFMA16(areg[(KS) & 1][2], b0, acc[2][0]);                     \
      acc[2][1] = MFMA16(areg[(KS) & 1][2], b1, acc[2][1]);                     \
      acc[3][0] = MFMA16(areg[(KS) & 1][3], b0, acc[3][0]);                     \
      acc[3][1] = MFMA16(areg[(KS) & 1][3], b1, acc[3][1]);                     \
    }                                                                           \
    __builtin_amdgcn_s_setprio(0);                                              \
  }

  STEP(0, 5)
  STEP(1, 9)
  STEP(2, 9)
  STEP(3, 9)
  STEP(4, 9)
  STEP(5, 9)
  STEP(6, 9)
  STEP(7, 9)
  STEP(8, 9)
  STEP(9, 9)
  STEP(10, 9)
  STEP(11, 9)
  STEP(12, 9)
  STEP(13, 9)
  STEP(14, 9)
  STEP(15, 8)
#undef STEP

  // ---- column norms: 8 partials per col from transpose threads
  if (tid < 256) nrmP[tq][tc] = nrm;
  __syncthreads();
  if (tid < BC) {
    float s = 0.f;
#pragma unroll
    for (int t = 0; t < 8; ++t) s += nrmP[t][tid];
    rnS[tid] = rsqrtf(fmaxf(s, 1e-20f));
  }
  __syncthreads();
  float rn[2];
#pragma unroll
  for (int j = 0; j < 2; ++j) rn[j] = rnS[j * 16 + ll];

  // ---- labels for my 16 rows from the LDS byte map
  int lab[4][4];
#pragma unroll
  for (int i = 0; i < 4; ++i)
#pragma unroll
    for (int q = 0; q < 4; ++q)
      lab[i][q] = (int)labL[wv * 64 + i * 16 + lh * 4 + q] - 1;  // local col or -1

  // ---- logits: cos*rn -> clip -> margin at target -> *64; track col max
  float mx[2] = {-3.4e38f, -3.4e38f};
#pragma unroll
  for (int j = 0; j < 2; ++j) {
    const int jl = j * 16 + ll;
#pragma unroll
    for (int i = 0; i < 4; ++i) {
#pragma unroll
      for (int q = 0; q < 4; ++q) {
        float cosv = acc[i][j][q] * rn[j];
        cosv = fminf(fmaxf(cosv, -1.f), 1.f);
        float lg;
        if (lab[i][q] == jl) {
          const float s = sqrtf(fmaxf(1.f - cosv * cosv, 0.f));
          lg = cosv * COS_M - s * SIN_M;
        } else {
          lg = cosv;
        }
        lg *= SCALE;
        acc[i][j][q] = lg;
        mx[j] = fmaxf(mx[j], lg);
      }
    }
  }

  // ---- softmax over the 512 rows of each column (axis=0)
#pragma unroll
  for (int j = 0; j < 2; ++j) {
    mx[j] = fmaxf(mx[j], __shfl_xor(mx[j], 16, 64));
    mx[j] = fmaxf(mx[j], __shfl_xor(mx[j], 32, 64));
  }
  if (l < 16) {
#pragma unroll
    for (int j = 0; j < 2; ++j) red[wv][j * 16 + l] = mx[j];
  }
  __syncthreads();
  if (tid < BC) {
    float m = red[0][tid];
#pragma unroll
    for (int v2 = 1; v2 < 8; ++v2) m = fmaxf(m, red[v2][tid]);
    colv[tid] = m;
  }
  __syncthreads();
  float cmax[2];
#pragma unroll
  for (int j = 0; j < 2; ++j) cmax[j] = colv[j * 16 + ll];

  float sme[2] = {0.f, 0.f};
#pragma unroll
  for (int j = 0; j < 2; ++j)
#pragma unroll
    for (int i = 0; i < 4; ++i)
#pragma unroll
      for (int q = 0; q < 4; ++q) {
        const float e = __expf(acc[i][j][q] - cmax[j]);
        acc[i][j][q] = e;
        sme[j] += e;
      }
#pragma unroll
  for (int j = 0; j < 2; ++j) {
    sme[j] += __shfl_xor(sme[j], 16, 64);
    sme[j] += __shfl_xor(sme[j], 32, 64);
  }
  __syncthreads();
  if (l < 16) {
#pragma unroll
    for (int j = 0; j < 2; ++j) red[wv][j * 16 + l] = sme[j];
  }
  __syncthreads();
  if (tid < BC) {
    float s = 0.f;
#pragma unroll
    for (int v2 = 0; v2 < 8; ++v2) s += red[v2][tid];
    colv[tid] = s;
  }
  __syncthreads();

  float rs[2];
#pragma unroll
  for (int j = 0; j < 2; ++j) rs[j] = 1.0f / colv[j * 16 + ll];

#pragma unroll
  for (int j = 0; j < 2; ++j) {
    const int cj = c0 + j * 16 + ll;
#pragma unroll
    for (int i = 0; i < 4; ++i) {
#pragma unroll
      for (int q = 0; q < 4; ++q) {
        const int row = wv * 64 + i * 16 + lh * 4 + q;
        out[(size_t)row * NCLS + cj] = acc[i][j][q] * rs[j];
      }
    }
  }
}

extern "C" void kernel_launch(void* const* d_in, const int* in_sizes, int n_in,
                              void* d_out, int out_size, void* d_ws, size_t ws_size,
                              hipStream_t stream) {
  const float* emb = (const float*)d_in[0];   // [512][512]
  const float* w   = (const float*)d_in[1];   // [512][100000]
  const float* tgt = (const float*)d_in[2];   // [512][100000]
  float* out = (float*)d_out;                 // [512][100000]

  char* ws = (char*)d_ws;
  unsigned short* afrag = (unsigned short*)(ws + 4096);     // 512 KB

  prep_afrag<<<64, 512, 0, stream>>>(emb, afrag);
  arcface_fused<<<NBLK, 512, 0, stream>>>(w, tgt, afrag, out);
}